// Round 1
// baseline (1031.795 us; speedup 1.0000x reference)
//
#include <hip/hip_runtime.h>

#define NN 131072   // nodes
#define EE 262144   // edges
#define GG 4096     // graphs

__global__ void k_fill(float* p, int n, float v) {
    int i = blockIdx.x * 256 + threadIdx.x;
    if (i < n) p[i] = v;
}

__global__ void k_count(const int* dst, float* deg) {
    int e = blockIdx.x * 256 + threadIdx.x;
    if (e < EE) atomicAdd(&deg[dst[e]], 1.0f);
}

__global__ void k_rsqrt(float* deg) {
    int i = blockIdx.x * 256 + threadIdx.x;
    if (i < NN) deg[i] = rsqrtf(deg[i]);
}

// h1[i][j] = x[i] * W1[j]   (GCNConv(1,64) matmul, K=1)
__global__ void k_h1(const float* x, const float* W1, float* h1) {
    int idx = blockIdx.x * 256 + threadIdx.x;
    if (idx < NN * 64) {
        int i = idx >> 6, j = idx & 63;
        h1[idx] = x[i] * W1[j];
    }
}

// agg[i][j] = h[i][j]*dinv[i]^2 + b[j]   (self-loop + bias init)
template <int C>
__global__ void k_agg_init(const float* h, const float* dinv, const float* b, float* agg) {
    int idx = blockIdx.x * 256 + threadIdx.x;
    if (idx < NN * C) {
        int i = idx / C, j = idx % C;
        float di = dinv[i];
        agg[idx] = h[idx] * di * di + b[j];
    }
}

// agg[dst] += h[src] * dinv[src]*dinv[dst]
template <int C>
__global__ void k_scatter(const int* src, const int* dst, const float* dinv,
                          const float* h, float* agg) {
    int t = blockIdx.x * 256 + threadIdx.x;   // E*C <= 2^25, fits int
    if (t < EE * C) {
        int e = t / C, j = t % C;
        int s = src[e], d = dst[e];
        float coef = dinv[s] * dinv[d];
        atomicAdd(&agg[d * C + j], h[s * C + j] * coef);
    }
}

// C[N,OUT] = act(A[N,K]) @ W[K,OUT], 16 rows per block, K-chunks of 32 in LDS
template <int K, int OUT, bool RELU>
__global__ __launch_bounds__(256) void k_matmul(const float* A, const float* W, float* C) {
    const int ROWS = 16, KC = 32;
    const int RPT = ROWS * OUT / 256;        // rows per thread
    __shared__ float At[ROWS][KC];
    __shared__ float Wt[KC][OUT];
    int tid = threadIdx.x;
    int i0 = blockIdx.x * ROWS;
    int col = tid % OUT;
    int rbase = (tid / OUT) * RPT;
    float acc[RPT];
#pragma unroll
    for (int r = 0; r < RPT; ++r) acc[r] = 0.0f;

    for (int k0 = 0; k0 < K; k0 += KC) {
        __syncthreads();
        for (int idx = tid; idx < ROWS * KC; idx += 256) {
            int r = idx / KC, kk = idx % KC;
            float v = A[(i0 + r) * K + k0 + kk];
            if (RELU) v = fmaxf(v, 0.0f);
            At[r][kk] = v;
        }
        for (int idx = tid; idx < KC * OUT; idx += 256) {
            int kk = idx / OUT, c = idx % OUT;
            Wt[kk][c] = W[(k0 + kk) * OUT + c];
        }
        __syncthreads();
#pragma unroll
        for (int kk = 0; kk < KC; ++kk) {
#pragma unroll
            for (int r = 0; r < RPT; ++r)
                acc[r] += At[rbase + r][kk] * Wt[kk][col];
        }
    }
#pragma unroll
    for (int r = 0; r < RPT; ++r)
        C[(i0 + rbase + r) * OUT + col] = acc[r];
}

// conv3 self-loop+bias scattered straight into per-graph pooled sums
__global__ void k_self_pool(const float* h3, const float* dinv, const float* b3,
                            const int* batch, float* pooled) {
    int idx = blockIdx.x * 256 + threadIdx.x;  // N*256
    if (idx < NN * 256) {
        int i = idx >> 8, c = idx & 255;
        float di = dinv[i];
        atomicAdd(&pooled[batch[i] * 256 + c], h3[idx] * di * di + b3[c]);
    }
}

// conv3 edge contributions scattered straight into per-graph pooled sums
__global__ void k_scatter_pool(const int* src, const int* dst, const float* dinv,
                               const int* batch, const float* h3, float* pooled) {
    long t = (long)blockIdx.x * 256 + threadIdx.x;  // E*256
    if (t < (long)EE * 256) {
        int e = (int)(t >> 8), c = (int)(t & 255);
        int s = src[e], d = dst[e];
        float coef = dinv[s] * dinv[d];
        atomicAdd(&pooled[batch[d] * 256 + c], h3[s * 256 + c] * coef);
    }
}

__global__ void k_cnt(const int* batch, float* cnt) {
    int i = blockIdx.x * 256 + threadIdx.x;
    if (i < NN) atomicAdd(&cnt[batch[i]], 1.0f);
}

// per-graph head: mean -> fc1+relu -> fc2
__global__ __launch_bounds__(128) void k_head(const float* pooled, const float* cnt,
                                              const float* fc1W, const float* fc1b,
                                              const float* fc2W, const float* fc2b,
                                              float* out) {
    __shared__ float mean[256];
    __shared__ float g1[128];
    int g = blockIdx.x, t = threadIdx.x;
    float inv = 1.0f / fmaxf(cnt[g], 1.0f);
    mean[t]       = pooled[g * 256 + t]       * inv;
    mean[t + 128] = pooled[g * 256 + 128 + t] * inv;
    __syncthreads();
    float acc = fc1b[t];
    for (int j = 0; j < 256; ++j) acc += mean[j] * fc1W[j * 128 + t];
    g1[t] = fmaxf(acc, 0.0f);
    __syncthreads();
    if (t < 12) {
        float o = fc2b[t];
        for (int k = 0; k < 128; ++k) o += g1[k] * fc2W[k * 12 + t];
        out[g * 12 + t] = o;
    }
}

extern "C" void kernel_launch(void* const* d_in, const int* in_sizes, int n_in,
                              void* d_out, int out_size, void* d_ws, size_t ws_size,
                              hipStream_t stream) {
    const float* x     = (const float*)d_in[0];
    const int*   ei    = (const int*)d_in[1];
    const int*   batch = (const int*)d_in[2];
    const float* W1    = (const float*)d_in[3];
    const float* b1    = (const float*)d_in[4];
    const float* W2    = (const float*)d_in[5];
    const float* b2    = (const float*)d_in[6];
    const float* W3    = (const float*)d_in[7];
    const float* b3    = (const float*)d_in[8];
    const float* fc1W  = (const float*)d_in[9];
    const float* fc1b  = (const float*)d_in[10];
    const float* fc2W  = (const float*)d_in[11];
    const float* fc2b  = (const float*)d_in[12];
    float* out = (float*)d_out;

    const int* srcp = ei;        // edge_index[0]
    const int* dstp = ei + EE;   // edge_index[1]

    float* ws     = (float*)d_ws;
    float* dinv   = ws;                          // N
    float* bufH   = dinv + NN;                   // N*256 (h1/h2/h3)
    float* bufA   = bufH + (size_t)NN * 256;     // N*128 (agg1/agg2)
    float* pooled = bufA + (size_t)NN * 128;     // G*256
    float* cnt    = pooled + (size_t)GG * 256;   // G

    // degree + rsqrt
    k_fill<<<(NN + 255) / 256, 256, 0, stream>>>(dinv, NN, 1.0f);
    k_fill<<<(GG * 256 + GG + 255) / 256, 256, 0, stream>>>(pooled, GG * 256 + GG, 0.0f);
    k_count<<<EE / 256, 256, 0, stream>>>(dstp, dinv);
    k_rsqrt<<<NN / 256, 256, 0, stream>>>(dinv);

    // conv1: h1 = x@W1 ; agg1 = scatter + self + b1
    k_h1<<<NN * 64 / 256, 256, 0, stream>>>(x, W1, bufH);
    k_agg_init<64><<<NN * 64 / 256, 256, 0, stream>>>(bufH, dinv, b1, bufA);
    k_scatter<64><<<EE * 64 / 256, 256, 0, stream>>>(srcp, dstp, dinv, bufH, bufA);

    // conv2: h2 = relu(agg1)@W2 ; agg2 = scatter + self + b2
    k_matmul<64, 128, true><<<NN / 16, 256, 0, stream>>>(bufA, W2, bufH);
    k_agg_init<128><<<NN * 128 / 256, 256, 0, stream>>>(bufH, dinv, b2, bufA);
    k_scatter<128><<<EE * 128 / 256, 256, 0, stream>>>(srcp, dstp, dinv, bufH, bufA);

    // conv3: h3 = relu(agg2)@W3 ; agg3 fused directly into pooled sums
    k_matmul<128, 256, true><<<NN / 16, 256, 0, stream>>>(bufA, W3, bufH);
    k_self_pool<<<NN * 256 / 256, 256, 0, stream>>>(bufH, dinv, b3, batch, pooled);
    k_scatter_pool<<<EE, 256, 0, stream>>>(srcp, dstp, dinv, batch, bufH, pooled);
    k_cnt<<<NN / 256, 256, 0, stream>>>(batch, cnt);

    // head
    k_head<<<GG, 128, 0, stream>>>(pooled, cnt, fc1W, fc1b, fc2W, fc2b, out);
}